// Round 7
// baseline (729.904 us; speedup 1.0000x reference)
//
#include <hip/hip_runtime.h>
#include <math.h>

#define NN 50000
#define NE 600000
#define ADIM 75
#define HID 128
#define NLAYERS 4
#define NGRAPHS 128
#define BN_EPS 1e-5f
#define NNP 50048   // NN padded to 128-node blocks (50048 = 391*128)
#define NB128 (NNP / 128)   // 391 node-blocks

typedef short bhalf8 __attribute__((ext_vector_type(8)));
typedef float floatx4 __attribute__((ext_vector_type(4)));

__device__ __forceinline__ float sigm(float v) { return 1.0f / (1.0f + __expf(-v)); }
__device__ __forceinline__ float tanh_f(float v) {
    return 1.0f - 2.0f / (__expf(2.0f * v) + 1.0f);
}

// fp32 -> bf16 with round-to-nearest-even
__device__ __forceinline__ unsigned short f2bf(float f) {
    unsigned u = __builtin_bit_cast(unsigned, f);
    u = (u + 0x7FFFu + ((u >> 16) & 1u)) >> 16;
    return (unsigned short)u;
}
__device__ __forceinline__ float bf2f(unsigned short h) {
    return __builtin_bit_cast(float, ((unsigned)h) << 16);
}

// async global->LDS, 16B per lane. LDS dest is wave-uniform base + lane*16;
// global src is per-lane (must already include +lane*16).
__device__ __forceinline__ void gl2lds16(const void* g, void* l) {
    __builtin_amdgcn_global_load_lds(
        (const __attribute__((address_space(1))) unsigned int*)g,
        (__attribute__((address_space(3))) unsigned int*)l, 16, 0, 0);
}

// ---------------------------------------------------------------------------
// nf [NN x 75] fp32 -> nfb [NNP x 96] bf16 (K zero-padded 75->96)
// ---------------------------------------------------------------------------
__global__ __launch_bounds__(256) void k_nfb(
    const float* __restrict__ nf, unsigned short* __restrict__ nfb)
{
    int e = blockIdx.x * 256 + threadIdx.x;      // (n, k4): 50000*24
    if (e >= NN * 24) return;
    int n = e / 24, k4 = e - n * 24;
    ushort4 o;
    int k = k4 * 4;
    o.x = (k + 0 < ADIM) ? f2bf(nf[(size_t)n * ADIM + k + 0]) : 0;
    o.y = (k + 1 < ADIM) ? f2bf(nf[(size_t)n * ADIM + k + 1]) : 0;
    o.z = (k + 2 < ADIM) ? f2bf(nf[(size_t)n * ADIM + k + 2]) : 0;
    o.w = (k + 3 < ADIM) ? f2bf(nf[(size_t)n * ADIM + k + 3]) : 0;
    ((ushort4*)nfb)[(size_t)n * 24 + k4] = o;
}

// ---------------------------------------------------------------------------
// embW [128 x 75] -> bf16 B-fragments, K padded to 96:
//   layout [tc(8)][kb(3)][quad(4)][n(16)][j(8)], elem = W[tc*16+n][kb*32+quad*8+j]
// ---------------------------------------------------------------------------
__global__ __launch_bounds__(256) void k_wfrag_emb(
    const float* __restrict__ W, unsigned short* __restrict__ web)
{
    int e = blockIdx.x * 256 + threadIdx.x;      // 0..12287
    int j = e & 7, n = (e >> 3) & 15, quad = (e >> 7) & 3;
    int kb = (e >> 9) % 3, tc = e / 1536;
    int row = tc * 16 + n;
    int kk = kb * 32 + quad * 8 + j;
    web[e] = (kk < ADIM) ? f2bf(W[row * ADIM + kk]) : 0;
}

// ---------------------------------------------------------------------------
// MFMA embedding — 512 threads (8 waves), 128 nodes/block, grid 391.
// (Unchanged from R20, which passed.)
// ---------------------------------------------------------------------------
__global__ __launch_bounds__(512) void k_embed_m(
    const unsigned short* __restrict__ nfb, const unsigned short* __restrict__ web,
    const float* __restrict__ b, float* __restrict__ y,
    float* __restrict__ bnsum)
{
    __shared__ __align__(16) unsigned short wbe[12288];    // 24 KB emb B-frags
    __shared__ float sred[1024], sred2[1024];              // 8 KB BN partials
    const int t = threadIdx.x;
    const int wave = t >> 6, lane = t & 63;
    const int col = lane & 15, quad = (lane >> 4) & 3;
    const int node0 = blockIdx.x * 128;

    // stage web: 24576 B = 8 waves x 3 KB, identity copy
    {
        const char* gsrc = (const char*)web + wave * 3072 + lane * 16;
        char* ldst = (char*)wbe + wave * 3072;
#pragma unroll
        for (int i = 0; i < 3; i++)
            gl2lds16(gsrc + i * 1024, ldst + i * 1024);
    }

    const int anode = node0 + wave * 16 + col;
    bhalf8 afN[3];
#pragma unroll
    for (int kb = 0; kb < 3; kb++)
        afN[kb] = *(const bhalf8*)&nfb[(size_t)anode * 96 + kb * 32 + quad * 8];

    floatx4 acc[8];
#pragma unroll
    for (int tc = 0; tc < 8; tc++) {
        float bv = b[tc * 16 + col];
        acc[tc] = (floatx4){bv, bv, bv, bv};
    }
    __syncthreads();   // drains vmcnt -> wbe staged

#pragma unroll
    for (int tc = 0; tc < 8; tc++) {
        bhalf8 bfr[3];
#pragma unroll
        for (int kb = 0; kb < 3; kb++)
            bfr[kb] = *(const bhalf8*)&wbe[((tc * 3 + kb) * 64 + lane) * 8];
#pragma unroll
        for (int kb = 0; kb < 3; kb++)
            acc[tc] = __builtin_amdgcn_mfma_f32_16x16x32_bf16(afN[kb], bfr[kb], acc[tc], 0, 0, 0);
    }

    // relu + direct y stores + register BN partials
    float ps[8], ps2[8];
#pragma unroll
    for (int tc = 0; tc < 8; tc++) {
        ps[tc] = 0.f; ps2[tc] = 0.f;
#pragma unroll
        for (int e = 0; e < 4; e++) {
            float v = fmaxf(acc[tc][e], 0.0f);
            int nd = node0 + wave * 16 + quad * 4 + e;
            if (nd < NN) {
                y[(size_t)nd * HID + tc * 16 + col] = v;
                ps[tc] += v; ps2[tc] += v * v;
            }
        }
    }
#pragma unroll
    for (int tc = 0; tc < 8; tc++) {
        ps[tc]  += __shfl_xor(ps[tc], 16);  ps2[tc] += __shfl_xor(ps2[tc], 16);
        ps[tc]  += __shfl_xor(ps[tc], 32);  ps2[tc] += __shfl_xor(ps2[tc], 32);
    }
    if (quad == 0) {
#pragma unroll
        for (int tc = 0; tc < 8; tc++) {
            sred[wave * 128 + tc * 16 + col]  = ps[tc];
            sred2[wave * 128 + tc * 16 + col] = ps2[tc];
        }
    }
    __syncthreads();
    if (t < 128) {
        float s = 0.f, s2 = 0.f;
#pragma unroll
        for (int w = 0; w < 8; w++) { s += sred[w * 128 + t]; s2 += sred2[w * 128 + t]; }
        unsafeAtomicAdd(&bnsum[t], s);
        unsafeAtomicAdd(&bnsum[128 + t], s2);
    }
}

// ---------------------------------------------------------------------------
// Fused BN-finalize + BN-apply + bf16 mirror + attention projections.
// (Unchanged from R20, which passed.)
// ---------------------------------------------------------------------------
__global__ __launch_bounds__(256) void k_bnx(
    const float* __restrict__ y, const float* __restrict__ bnsum,
    const float* __restrict__ g, const float* __restrict__ beta,
    const float* __restrict__ attW,
    unsigned short* __restrict__ xb,
    float* __restrict__ as_, float* __restrict__ ad_)
{
    const int t = threadIdx.x;
    const int n = blockIdx.x * 4 + (t >> 6);
    const int lane = t & 63;
    const int f0 = lane * 2;
    float m0 = bnsum[f0] * (1.0f / NN);
    float v0 = bnsum[128 + f0] * (1.0f / NN) - m0 * m0;
    float m1 = bnsum[f0 + 1] * (1.0f / NN);
    float v1 = bnsum[128 + f0 + 1] * (1.0f / NN) - m1 * m1;
    float sc0 = g[f0] * rsqrtf(v0 + BN_EPS);
    float sc1 = g[f0 + 1] * rsqrtf(v1 + BN_EPS);
    float sh0 = beta[f0] - m0 * sc0;
    float sh1 = beta[f0 + 1] - m1 * sc1;

    float2 v = ((const float2*)y)[(size_t)n * 64 + lane];
    float2 xv;
    xv.x = v.x * sc0 + sh0;
    xv.y = v.y * sc1 + sh1;
    unsigned pk = (unsigned)f2bf(xv.x) | ((unsigned)f2bf(xv.y) << 16);
    ((unsigned*)xb)[(size_t)n * 64 + lane] = pk;
    float2 aws = ((const float2*)attW)[lane];
    float2 awd = ((const float2*)(attW + 128))[lane];
    float pas = xv.x * aws.x + xv.y * aws.y;
    float pad = xv.x * awd.x + xv.y * awd.y;
#pragma unroll
    for (int msk = 32; msk >= 1; msk >>= 1) {
        pas += __shfl_xor(pas, msk);
        pad += __shfl_xor(pad, msk);
    }
    if (lane == 0) { as_[n] = pas; ad_[n] = pad; }
}

// ---------------------------------------------------------------------------
// Combined-weight precompute: Wc[l] = Wih[l] @ Wm[l], bmih[l] = Wih[l] @ bm[l]
// ---------------------------------------------------------------------------
__global__ __launch_bounds__(128) void k_wc(
    const float* __restrict__ Wih, const float* __restrict__ Wm,
    const float* __restrict__ bm, float* __restrict__ Wc, float* __restrict__ bmih)
{
    __shared__ float sw[128];
    __shared__ float red[128];
    const int b = blockIdx.x;
    const int l = b / 384, r = b - l * 384;
    const int t = threadIdx.x;
    const float* wihrow = Wih + ((size_t)l * 384 + r) * 128;
    sw[t] = wihrow[t];
    __syncthreads();
    const float* wm = Wm + (size_t)l * 128 * 128;
    float acc = 0.f;
#pragma unroll 8
    for (int k = 0; k < 128; k++) acc += sw[k] * wm[k * 128 + t];
    Wc[((size_t)l * 384 + r) * 128 + t] = acc;
    red[t] = sw[t] * bm[l * 128 + t];
    __syncthreads();
#pragma unroll
    for (int off = 64; off >= 1; off >>= 1) {
        if (t < off) red[t] += red[t + off];
        __syncthreads();
    }
    if (t == 0) bmih[l * 384 + r] = red[0];
}

// ---------------------------------------------------------------------------
// Convert Wc (fp32) and Whh to bf16 in MFMA B-fragment order:
//   layout [gate(3)][tc(8)][kb(4)][quad(4)][n(16)][j(8)] per layer-matrix
// ---------------------------------------------------------------------------
__global__ __launch_bounds__(256) void k_frag(
    const float* __restrict__ Wc, const float* __restrict__ Whh,
    unsigned short* __restrict__ wcb, unsigned short* __restrict__ whhb)
{
    const int b = blockIdx.x;
    const int mat = b / 192;
    const int e = (b - mat * 192) * 256 + threadIdx.x;   // 0..49151
    const int l = mat >> 1, which = mat & 1;
    const float* src = which ? (Whh + (size_t)l * 49152) : (Wc + (size_t)l * 49152);
    unsigned short* dst = which ? (whhb + (size_t)l * 49152) : (wcb + (size_t)l * 49152);
    int j = e & 7, n = (e >> 3) & 15, quad = (e >> 7) & 3;
    int kb = (e >> 9) & 3, tc = (e >> 11) & 7, g = (e >> 14) & 3;
    int row = g * 128 + tc * 16 + n;
    int kk = kb * 32 + quad * 8 + j;
    dst[e] = f2bf(src[row * 128 + kk]);
}

// ---------------------------------------------------------------------------
// CSR build: histogram, 3-kernel device-wide scan, scatter
// ---------------------------------------------------------------------------
__global__ __launch_bounds__(256) void k_count(const int* __restrict__ dst, int* __restrict__ cnt)
{
    int e = blockIdx.x * 256 + threadIdx.x;
    if (e < NE) atomicAdd(&cnt[dst[e]], 1);
}

#define SCAN_B 512
#define SCAN_G 98          // 98*512 = 50176 >= 50000

__global__ __launch_bounds__(SCAN_B) void k_scan1(
    const int* __restrict__ cnt, int* __restrict__ rowptr, int* __restrict__ bsum)
{
    __shared__ int s[SCAN_B];
    const int t = threadIdx.x;
    const int i = blockIdx.x * SCAN_B + t;
    int v = (i < NN) ? cnt[i] : 0;
    s[t] = v;
    __syncthreads();
#pragma unroll
    for (int off = 1; off < SCAN_B; off <<= 1) {
        int u = (t >= off) ? s[t - off] : 0;
        __syncthreads();
        s[t] += u;
        __syncthreads();
    }
    if (i < NN) rowptr[i] = s[t] - v;        // local exclusive
    if (t == SCAN_B - 1) bsum[blockIdx.x] = s[t];
}

__global__ __launch_bounds__(128) void k_scan2(int* __restrict__ bsum, int* __restrict__ rowptr)
{
    __shared__ int s[128];
    const int t = threadIdx.x;
    int v = (t < SCAN_G) ? bsum[t] : 0;
    s[t] = v;
    __syncthreads();
#pragma unroll
    for (int off = 1; off < 128; off <<= 1) {
        int u = (t >= off) ? s[t - off] : 0;
        __syncthreads();
        s[t] += u;
        __syncthreads();
    }
    if (t < SCAN_G) bsum[t] = s[t] - v;      // exclusive offsets
    if (t == 127) rowptr[NN] = s[127];       // grand total (= NE)
}

__global__ __launch_bounds__(SCAN_B) void k_scan3(
    int* __restrict__ rowptr, const int* __restrict__ bsum, int* __restrict__ wptr)
{
    const int i = blockIdx.x * SCAN_B + threadIdx.x;
    if (i < NN) {
        int v = rowptr[i] + bsum[blockIdx.x];
        rowptr[i] = v;
        wptr[i] = v;
    }
}

__global__ __launch_bounds__(256) void k_scatter(
    const int* __restrict__ src, const int* __restrict__ dst,
    int* __restrict__ wptr, int* __restrict__ ssrc)
{
    int e = blockIdx.x * 256 + threadIdx.x;
    if (e < NE) {
        int d = dst[e];
        int pos = atomicAdd(&wptr[d], 1);
        ssrc[pos] = src[e];
    }
}

// ---------------------------------------------------------------------------
// R22: FUSED gather+GRU, one regular kernel per layer (NO cooperative launch).
// R21 post-mortem: the cooperative all-layers kernel failed correctness; it
// bundled 3 untested changes (grid.sync, in-kernel Phase B, LDS swizzle).
// This round takes only the fence-free half: gather reads neighbor xb which
// is complete at KERNEL ENTRY (k_bnx of the previous layer ended), so
// gather+GRU need no grid sync. Agg goes through LDS LINEARLY (128 rows x
// 256 B) — afA read has a ~16-way bank conflict on 4 ds_read_b128/lane,
// ~300 cy/wave, noise vs the ~16 us latency-bound block. Eliminates the
// aggxb+sumatt round-trip (~102 MB) and 4 dispatches; gather-phase blocks
// overlap GRU-phase blocks on the CU.
// Geometry: 512 thr (8 waves), 128 nodes/block, grid 391 (R20 proven).
// LDS: sbuf 32 KB (agg, then reused for weight stages) + sred 8 KB + satt.
// R19 lesson: per-wave registers unchanged. R11/R13: no occupancy forcing.
// ---------------------------------------------------------------------------
#define STAGE_W(SRC)                                                          \
    {                                                                         \
        const char* gsrc = (const char*)(SRC) + wave * 4096 + lane * 16;      \
        char* ldst = (char*)sbuf + wave * 4096;                               \
        _Pragma("unroll")                                                     \
        for (int i = 0; i < 4; i++)                                           \
            gl2lds16(gsrc + i * 1024, ldst + i * 1024);                       \
    }

#define MMGL(AF, ACC)                                                         \
    _Pragma("unroll")                                                         \
    for (int tc = 0; tc < 8; tc++) {                                          \
        bhalf8 bfr[4];                                                        \
        _Pragma("unroll")                                                     \
        for (int kb = 0; kb < 4; kb++)                                        \
            bfr[kb] = *(const bhalf8*)&sbuf[((tc * 4 + kb) * 64 + lane) * 8]; \
        _Pragma("unroll")                                                     \
        for (int kb = 0; kb < 4; kb++)                                        \
            ACC[tc] = __builtin_amdgcn_mfma_f32_16x16x32_bf16(AF[kb], bfr[kb], ACC[tc], 0, 0, 0); \
    }

__global__ __launch_bounds__(512) void k_ggru(
    const int* __restrict__ rowptr, const int* __restrict__ ssrc,
    const float* __restrict__ as_, const float* __restrict__ ad_,
    const float* __restrict__ attb, int l,
    const unsigned short* __restrict__ xb,
    const unsigned short* __restrict__ wcb, const float* __restrict__ bmih,
    const float* __restrict__ bih,
    const unsigned short* __restrict__ whhb, const float* __restrict__ bhh,
    float* __restrict__ y, float* __restrict__ bnsum)
{
    __shared__ __align__(16) unsigned short sbuf[16384];   // 32 KB agg->weights
    __shared__ float sred[1024], sred2[1024];              // 8 KB BN partials
    __shared__ float satt[128];                            // per-node sum-att
    const int t = threadIdx.x;
    const int wave = t >> 6, lane = t & 63;
    const int col = lane & 15, quad = (lane >> 4) & 3;
    const int node0 = blockIdx.x * 128;

    // ===== Phase G: gather own 128 nodes -> sbuf (bf16, LINEAR rows) =====
    {
        const float ab = attb[l];
        const int lane32 = t & 31;
        const int g16 = t >> 5;                 // 16 concurrent node-slots
        for (int it = 0; it < 8; ++it) {
            const int nl = it * 16 + g16;       // local node 0..127
            const int n = node0 + nl;
            int r0 = 0, r1 = 0; float adv = 0.f;
            if (n < NN) { r0 = rowptr[n]; r1 = rowptr[n + 1]; adv = ad_[n] + ab; }
            float4 acc = make_float4(0.f, 0.f, 0.f, 0.f);
            float sat = 0.f;
            int ids[8], ids2[8];
            if (r0 < r1) {
#pragma unroll
                for (int k = 0; k < 8; k++) {
                    int idx = r0 + k; if (idx >= r1) idx = r1 - 1;
                    ids[k] = ssrc[idx];
                }
            }
            for (int base = r0; base < r1; base += 8) {
                const int nxt = base + 8;
                if (nxt < r1) {
#pragma unroll
                    for (int k = 0; k < 8; k++) {
                        int idx = nxt + k; if (idx >= r1) idx = r1 - 1;
                        ids2[k] = ssrc[idx];
                    }
                }
                ushort4 v[8];
                float a[8];
#pragma unroll
                for (int k = 0; k < 8; k++) {
                    v[k] = ((const ushort4*)xb)[(size_t)ids[k] * 32 + lane32];
                    a[k] = as_[ids[k]];
                }
#pragma unroll
                for (int k = 0; k < 8; k++) {
                    if (base + k < r1) {
                        float att = sigm(a[k] + adv);
                        acc.x += bf2f(v[k].x) * att; acc.y += bf2f(v[k].y) * att;
                        acc.z += bf2f(v[k].z) * att; acc.w += bf2f(v[k].w) * att;
                        sat += att;
                    }
                }
#pragma unroll
                for (int k = 0; k < 8; k++) ids[k] = ids2[k];
            }
            ushort4 o;
            o.x = f2bf(acc.x); o.y = f2bf(acc.y); o.z = f2bf(acc.z); o.w = f2bf(acc.w);
            *(ushort4*)((char*)sbuf + (unsigned)nl * 256u + (unsigned)lane32 * 8u) = o;
            if (lane32 == 0) satt[nl] = sat;
        }
    }
    __syncthreads();                       // agg + satt visible to all waves

    // ===== A-fragments: afA from LDS agg, afX from global xb =====
    bhalf8 afA[4], afX[4];
    {
        const int rloc = wave * 16 + col;
#pragma unroll
        for (int kb = 0; kb < 4; kb++) {
            afA[kb] = *(const bhalf8*)((const char*)sbuf +
                       (unsigned)rloc * 256u + (unsigned)(kb * 64 + quad * 16));
            afX[kb] = *(const bhalf8*)&xb[(size_t)(node0 + rloc) * HID + kb * 32 + quad * 8];
        }
    }
    float sa[4];
#pragma unroll
    for (int e = 0; e < 4; e++) sa[e] = satt[wave * 16 + quad * 4 + e];
    __syncthreads();                       // agg consumed -> sbuf reusable

    floatx4 accR[8], accN[8];

    // ===== gate r: merged accumulator (gi+gh) =====
    STAGE_W(wcb + 0 * 16384);
#pragma unroll
    for (int tc = 0; tc < 8; tc++) {
        int f = 0 * 128 + tc * 16 + col;
        float b0 = bih[f] + bhh[f], bm = bmih[f];
        accR[tc] = (floatx4){b0 + sa[0] * bm, b0 + sa[1] * bm, b0 + sa[2] * bm, b0 + sa[3] * bm};
    }
    __syncthreads();                 // wcb[r] staged (drains vmcnt)
    MMGL(afA, accR);
    __syncthreads();                 // all waves done reading
    STAGE_W(whhb + 0 * 16384);
    __syncthreads();
    MMGL(afX, accR);
    __syncthreads();
    STAGE_W(whhb + 2 * 16384);       // prefetch gate-n Whh; sigm overlaps
#pragma unroll
    for (int tc = 0; tc < 8; tc++)
#pragma unroll
        for (int e = 0; e < 4; e++)
            accR[tc][e] = sigm(accR[tc][e]);          // accR now holds r

    // ===== gate n: acc = afX@Whh + bh; acc = r*acc + bi + sa*bm; acc += afA@Wc =====
#pragma unroll
    for (int tc = 0; tc < 8; tc++) {
        float bh = bhh[2 * 128 + tc * 16 + col];
        accN[tc] = (floatx4){bh, bh, bh, bh};
    }
    __syncthreads();
    MMGL(afX, accN);
    __syncthreads();
    STAGE_W(wcb + 2 * 16384);        // prefetch gate-n Wc; r-merge overlaps
#pragma unroll
    for (int tc = 0; tc < 8; tc++) {
        int f = 2 * 128 + tc * 16 + col;
        float bi = bih[f], bm = bmih[f];
#pragma unroll
        for (int e = 0; e < 4; e++)
            accN[tc][e] = accR[tc][e] * accN[tc][e] + bi + sa[e] * bm;
    }
    __syncthreads();
    MMGL(afA, accN);
    __syncthreads();
    STAGE_W(wcb + 1 * 16384);        // prefetch gate-z Wc; tanh overlaps
#pragma unroll
    for (int tc = 0; tc < 8; tc++)
#pragma unroll
        for (int e = 0; e < 4; e++)
            accN[tc][e] = tanh_f(accN[tc][e]);        // accN now holds n

    // ===== gate z: merged accumulator (reuse accR) =====
#pragma unroll
    for (int tc = 0; tc < 8; tc++) {
        int f = 1 * 128 + tc * 16 + col;
        float b0 = bih[f] + bhh[f], bm = bmih[f];
        accR[tc] = (floatx4){b0 + sa[0] * bm, b0 + sa[1] * bm, b0 + sa[2] * bm, b0 + sa[3] * bm};
    }
    __syncthreads();
    MMGL(afA, accR);
    __syncthreads();
    STAGE_W(whhb + 1 * 16384);
    __syncthreads();
    MMGL(afX, accR);

    // ===== h = (1-z)*n + z*x; direct y stores; register BN partials =====
    float ps[8], ps2[8];
#pragma unroll
    for (int tc = 0; tc < 8; tc++) {
        ps[tc] = 0.f; ps2[tc] = 0.f;
#pragma unroll
        for (int e = 0; e < 4; e++) {
            float z = sigm(accR[tc][e]);
            int nd = node0 + wave * 16 + quad * 4 + e;
            float xv = bf2f(xb[(size_t)nd * HID + tc * 16 + col]);
            float h = (1.0f - z) * accN[tc][e] + z * xv;
            if (nd < NN) {
                y[(size_t)nd * HID + tc * 16 + col] = h;
                ps[tc] += h; ps2[tc] += h * h;
            }
        }
    }
#pragma unroll
    for (int tc = 0; tc < 8; tc++) {
        ps[tc]  += __shfl_xor(ps[tc], 16);  ps2[tc] += __shfl_xor(ps2[tc], 16);
        ps[tc]  += __shfl_xor(ps[tc], 32);  ps2[tc] += __shfl_xor(ps2[tc], 32);
    }
    if (quad == 0) {
#pragma unroll
        for (int tc = 0; tc < 8; tc++) {
            sred[wave * 128 + tc * 16 + col]  = ps[tc];
            sred2[wave * 128 + tc * 16 + col] = ps2[tc];
        }
    }
    __syncthreads();
    if (t < 128) {
        float s = 0.f, s2 = 0.f;
#pragma unroll
        for (int w = 0; w < 8; w++) { s += sred[w * 128 + t]; s2 += sred2[w * 128 + t]; }
        unsafeAtomicAdd(&bnsum[t], s);
        unsafeAtomicAdd(&bnsum[128 + t], s2);
    }
}

// ---------------------------------------------------------------------------
// Segmented sum-pool over bf16 xb (batch_idx is SORTED)
// ---------------------------------------------------------------------------
__global__ __launch_bounds__(256) void k_pool(
    const unsigned short* __restrict__ xb, const int* __restrict__ batch,
    float* __restrict__ gr)
{
    __shared__ int sb[256];
    const int t = threadIdx.x;
    const int nb = blockIdx.x * 256;
    int ld = nb + t; if (ld >= NN) ld = NN - 1;
    sb[t] = batch[ld];
    __syncthreads();
    const int s = t >> 7, f = t & 127;
    float acc = 0.f; int cur = -1;
    for (int i = s; i < 256; i += 2) {
        int n = nb + i;
        if (n >= NN) break;
        int g = sb[i];
        if (g != cur) {
            if (cur >= 0) unsafeAtomicAdd(&gr[(size_t)cur * HID + f], acc);
            acc = 0.f; cur = g;
        }
        acc += bf2f(xb[(size_t)n * HID + f]);
    }
    if (cur >= 0) unsafeAtomicAdd(&gr[(size_t)cur * HID + f], acc);
}

// ---------------------------------------------------------------------------
// Readout: out[g] = relu(gr[g] @ W1^T + b1) @ W2^T + b2   (128 blocks x 64)
// ---------------------------------------------------------------------------
__global__ __launch_bounds__(64) void k_readout(
    const float* __restrict__ gr, const float* __restrict__ W1,
    const float* __restrict__ b1, const float* __restrict__ W2,
    const float* __restrict__ b2, float* __restrict__ out)
{
    const int g = blockIdx.x, j = threadIdx.x;
    float acc = b1[j];
    const float4* grow = (const float4*)&gr[g * HID];
    const float4* wrow = (const float4*)&W1[j * HID];
#pragma unroll
    for (int k4 = 0; k4 < 32; k4++) {
        float4 a = grow[k4], w = wrow[k4];
        acc += a.x * w.x + a.y * w.y + a.z * w.z + a.w * w.w;
    }
    float h = fmaxf(acc, 0.0f) * W2[j];
#pragma unroll
    for (int msk = 32; msk >= 1; msk >>= 1) h += __shfl_xor(h, msk);
    if (j == 0) out[g] = h + b2[0];
}

// ---------------------------------------------------------------------------
extern "C" void kernel_launch(void* const* d_in, const int* in_sizes, int n_in,
                              void* d_out, int out_size, void* d_ws, size_t ws_size,
                              hipStream_t stream)
{
    const float* nf    = (const float*)d_in[0];
    const int*   ei    = (const int*)d_in[1];
    const int*   batch = (const int*)d_in[2];
    const float* embW  = (const float*)d_in[3];
    const float* embb  = (const float*)d_in[4];
    const float* embg  = (const float*)d_in[5];
    const float* embbe = (const float*)d_in[6];
    const float* msgW  = (const float*)d_in[7];
    const float* msgb  = (const float*)d_in[8];
    const float* attW  = (const float*)d_in[9];
    const float* attb  = (const float*)d_in[10];
    const float* Wih   = (const float*)d_in[11];
    const float* bih   = (const float*)d_in[12];
    const float* Whh   = (const float*)d_in[13];
    const float* bhh   = (const float*)d_in[14];
    const float* bng   = (const float*)d_in[15];
    const float* bnb   = (const float*)d_in[16];
    const float* roW1  = (const float*)d_in[17];
    const float* rob1  = (const float*)d_in[18];
    const float* roW2  = (const float*)d_in[19];
    const float* rob2  = (const float*)d_in[20];
    const int* src = ei;
    const int* dst = ei + NE;
    float* out = (float*)d_out;

    // ---- workspace layout (all sections 16B-multiple) ----
    char* base = (char*)d_ws;
    const size_t NH = (size_t)NN * HID;      // 6.4M elements
    float* bnsum = (float*)base;             // 5 slots x 256 floats (10240 B reserved)
    float* y     = (float*)(base + 10240);   // pre-BN state (NN*128 fp32)
    unsigned short* xb = (unsigned short*)(y + NH);      // bf16 node state (NNP rows)
    float* as_   = (float*)(xb + (size_t)NNP * HID);
    float* ad_   = as_ + NN;
    float* gr    = ad_ + NN;                 // 128*128
    float* Wc    = gr + NGRAPHS * HID;       // 4*384*128 fp32
    float* bmih  = Wc + 4 * 384 * 128;       // 4*384
    int* rowptr  = (int*)(bmih + 4 * 384);   // NN+4 (padded for alignment)
    int* wptr    = rowptr + NN + 4;          // NN
    int* cnt     = wptr + NN;                // NN
    int* bsum    = cnt + NN;                 // 128 (scan block totals)
    int* ssrc    = bsum + 128;               // NE
    unsigned short* wcb  = (unsigned short*)(ssrc + NE); // 4*49152 bf16 frags
    unsigned short* whhb = wcb + 4 * 49152;              // 4*49152 bf16 frags
    unsigned short* nfb  = whhb + 4 * 49152;             // NNP*96 bf16 padded nf
    unsigned short* web  = nfb + (size_t)NNP * 96;       // 12288 emb B-frags

    // ---- once-per-call precompute: weights (+bf16 frags), nf cast, CSR ----
    k_wc<<<4 * 384, 128, 0, stream>>>(Wih, msgW, msgb, Wc, bmih);
    k_frag<<<8 * 192, 256, 0, stream>>>(Wc, Whh, wcb, whhb);
    k_nfb<<<(NN * 24 + 255) / 256, 256, 0, stream>>>(nf, nfb);
    k_wfrag_emb<<<48, 256, 0, stream>>>(embW, web);
    hipMemsetAsync(cnt, 0, NN * sizeof(int), stream);
    hipMemsetAsync(bnsum, 0, 5 * 256 * sizeof(float), stream);
    k_count<<<(NE + 255) / 256, 256, 0, stream>>>(dst, cnt);
    k_scan1<<<SCAN_G, SCAN_B, 0, stream>>>(cnt, rowptr, bsum);
    k_scan2<<<1, 128, 0, stream>>>(bsum, rowptr);
    k_scan3<<<SCAN_G, SCAN_B, 0, stream>>>(rowptr, bsum, wptr);
    k_scatter<<<(NE + 255) / 256, 256, 0, stream>>>(src, dst, wptr, ssrc);

    // ---- MFMA embedding (BN sums -> slot 0) + fused BN/att-proj ----
    k_embed_m<<<NB128, 512, 0, stream>>>(nfb, web, embb, y, bnsum);
    k_bnx<<<NN / 4, 256, 0, stream>>>(y, bnsum, embg, embbe, attW, xb, as_, ad_);

    for (int l = 0; l < NLAYERS; l++) {
        k_ggru<<<NB128, 512, 0, stream>>>(
            rowptr, ssrc, as_, ad_, attb, l, xb,
            wcb + (size_t)l * 49152, bmih + (size_t)l * 384, bih + (size_t)l * 384,
            whhb + (size_t)l * 49152, bhh + (size_t)l * 384, y, bnsum + (l + 1) * 256);
        const float* attW_next = attW + (size_t)((l + 1 < NLAYERS) ? l + 1 : l) * 256;
        k_bnx<<<NN / 4, 256, 0, stream>>>(y, bnsum + (l + 1) * 256,
                                          bng + (size_t)l * HID, bnb + (size_t)l * HID,
                                          attW_next, xb, as_, ad_);
    }

    hipMemsetAsync(gr, 0, NGRAPHS * HID * sizeof(float), stream);
    k_pool<<<(NN + 255) / 256, 256, 0, stream>>>(xb, batch, gr);
    k_readout<<<NGRAPHS, 64, 0, stream>>>(gr, roW1, rob1, roW2, rob2, out);
}

// Round 8
// 617.058 us; speedup vs baseline: 1.1829x; 1.1829x over previous
//
#include <hip/hip_runtime.h>
#include <math.h>

#define NN 50000
#define NE 600000
#define ADIM 75
#define HID 128
#define NLAYERS 4
#define NGRAPHS 128
#define BN_EPS 1e-5f
#define NNP 50048   // NN padded to 128-node blocks (50048 = 391*128)
#define NB128 (NNP / 128)   // 391 node-blocks

typedef short bhalf8 __attribute__((ext_vector_type(8)));
typedef float floatx4 __attribute__((ext_vector_type(4)));

__device__ __forceinline__ float sigm(float v) { return 1.0f / (1.0f + __expf(-v)); }
__device__ __forceinline__ float tanh_f(float v) {
    return 1.0f - 2.0f / (__expf(2.0f * v) + 1.0f);
}

// fp32 -> bf16 with round-to-nearest-even
__device__ __forceinline__ unsigned short f2bf(float f) {
    unsigned u = __builtin_bit_cast(unsigned, f);
    u = (u + 0x7FFFu + ((u >> 16) & 1u)) >> 16;
    return (unsigned short)u;
}
__device__ __forceinline__ float bf2f(unsigned short h) {
    return __builtin_bit_cast(float, ((unsigned)h) << 16);
}

// async global->LDS, 16B per lane. LDS dest is wave-uniform base + lane*16;
// global src is per-lane (must already include +lane*16).
__device__ __forceinline__ void gl2lds16(const void* g, void* l) {
    __builtin_amdgcn_global_load_lds(
        (const __attribute__((address_space(1))) unsigned int*)g,
        (__attribute__((address_space(3))) unsigned int*)l, 16, 0, 0);
}

// ---------------------------------------------------------------------------
// nf [NN x 75] fp32 -> nfb [NNP x 96] bf16 (K zero-padded 75->96)
// ---------------------------------------------------------------------------
__global__ __launch_bounds__(256) void k_nfb(
    const float* __restrict__ nf, unsigned short* __restrict__ nfb)
{
    int e = blockIdx.x * 256 + threadIdx.x;      // (n, k4): 50000*24
    if (e >= NN * 24) return;
    int n = e / 24, k4 = e - n * 24;
    ushort4 o;
    int k = k4 * 4;
    o.x = (k + 0 < ADIM) ? f2bf(nf[(size_t)n * ADIM + k + 0]) : 0;
    o.y = (k + 1 < ADIM) ? f2bf(nf[(size_t)n * ADIM + k + 1]) : 0;
    o.z = (k + 2 < ADIM) ? f2bf(nf[(size_t)n * ADIM + k + 2]) : 0;
    o.w = (k + 3 < ADIM) ? f2bf(nf[(size_t)n * ADIM + k + 3]) : 0;
    ((ushort4*)nfb)[(size_t)n * 24 + k4] = o;
}

// ---------------------------------------------------------------------------
// embW [128 x 75] -> bf16 B-fragments, K padded to 96:
//   layout [tc(8)][kb(3)][quad(4)][n(16)][j(8)], elem = W[tc*16+n][kb*32+quad*8+j]
// ---------------------------------------------------------------------------
__global__ __launch_bounds__(256) void k_wfrag_emb(
    const float* __restrict__ W, unsigned short* __restrict__ web)
{
    int e = blockIdx.x * 256 + threadIdx.x;      // 0..12287
    int j = e & 7, n = (e >> 3) & 15, quad = (e >> 7) & 3;
    int kb = (e >> 9) % 3, tc = e / 1536;
    int row = tc * 16 + n;
    int kk = kb * 32 + quad * 8 + j;
    web[e] = (kk < ADIM) ? f2bf(W[row * ADIM + kk]) : 0;
}

// ---------------------------------------------------------------------------
// MFMA embedding — 512 threads (8 waves), 128 nodes/block, grid 391.
// R23: pre-BN state y stored as BF16 (y16) — halves the y stream; BN
// partials computed from the ROUNDED value for self-consistency.
// ---------------------------------------------------------------------------
__global__ __launch_bounds__(512) void k_embed_m(
    const unsigned short* __restrict__ nfb, const unsigned short* __restrict__ web,
    const float* __restrict__ b, unsigned short* __restrict__ y16,
    float* __restrict__ bnsum)
{
    __shared__ __align__(16) unsigned short wbe[12288];    // 24 KB emb B-frags
    __shared__ float sred[1024], sred2[1024];              // 8 KB BN partials
    const int t = threadIdx.x;
    const int wave = t >> 6, lane = t & 63;
    const int col = lane & 15, quad = (lane >> 4) & 3;
    const int node0 = blockIdx.x * 128;

    // stage web: 24576 B = 8 waves x 3 KB, identity copy
    {
        const char* gsrc = (const char*)web + wave * 3072 + lane * 16;
        char* ldst = (char*)wbe + wave * 3072;
#pragma unroll
        for (int i = 0; i < 3; i++)
            gl2lds16(gsrc + i * 1024, ldst + i * 1024);
    }

    const int anode = node0 + wave * 16 + col;
    bhalf8 afN[3];
#pragma unroll
    for (int kb = 0; kb < 3; kb++)
        afN[kb] = *(const bhalf8*)&nfb[(size_t)anode * 96 + kb * 32 + quad * 8];

    floatx4 acc[8];
#pragma unroll
    for (int tc = 0; tc < 8; tc++) {
        float bv = b[tc * 16 + col];
        acc[tc] = (floatx4){bv, bv, bv, bv};
    }
    __syncthreads();   // drains vmcnt -> wbe staged

#pragma unroll
    for (int tc = 0; tc < 8; tc++) {
        bhalf8 bfr[3];
#pragma unroll
        for (int kb = 0; kb < 3; kb++)
            bfr[kb] = *(const bhalf8*)&wbe[((tc * 3 + kb) * 64 + lane) * 8];
#pragma unroll
        for (int kb = 0; kb < 3; kb++)
            acc[tc] = __builtin_amdgcn_mfma_f32_16x16x32_bf16(afN[kb], bfr[kb], acc[tc], 0, 0, 0);
    }

    // relu + bf16 y stores + register BN partials (from rounded value)
    float ps[8], ps2[8];
#pragma unroll
    for (int tc = 0; tc < 8; tc++) {
        ps[tc] = 0.f; ps2[tc] = 0.f;
#pragma unroll
        for (int e = 0; e < 4; e++) {
            float v = fmaxf(acc[tc][e], 0.0f);
            int nd = node0 + wave * 16 + quad * 4 + e;
            if (nd < NN) {
                unsigned short vb = f2bf(v);
                float vr = bf2f(vb);
                y16[(size_t)nd * HID + tc * 16 + col] = vb;
                ps[tc] += vr; ps2[tc] += vr * vr;
            }
        }
    }
#pragma unroll
    for (int tc = 0; tc < 8; tc++) {
        ps[tc]  += __shfl_xor(ps[tc], 16);  ps2[tc] += __shfl_xor(ps2[tc], 16);
        ps[tc]  += __shfl_xor(ps[tc], 32);  ps2[tc] += __shfl_xor(ps2[tc], 32);
    }
    if (quad == 0) {
#pragma unroll
        for (int tc = 0; tc < 8; tc++) {
            sred[wave * 128 + tc * 16 + col]  = ps[tc];
            sred2[wave * 128 + tc * 16 + col] = ps2[tc];
        }
    }
    __syncthreads();
    if (t < 128) {
        float s = 0.f, s2 = 0.f;
#pragma unroll
        for (int w = 0; w < 8; w++) { s += sred[w * 128 + t]; s2 += sred2[w * 128 + t]; }
        unsafeAtomicAdd(&bnsum[t], s);
        unsafeAtomicAdd(&bnsum[128 + t], s2);
    }
}

// ---------------------------------------------------------------------------
// Fused BN-finalize + BN-apply + bf16 mirror + attention projections.
// R23: reads y16 (bf16); do_proj=0 skips the dead projections after the
// last layer (as_/ad_ unused then).
// ---------------------------------------------------------------------------
__global__ __launch_bounds__(256) void k_bnx(
    const unsigned short* __restrict__ y16, const float* __restrict__ bnsum,
    const float* __restrict__ g, const float* __restrict__ beta,
    const float* __restrict__ attW, int do_proj,
    unsigned short* __restrict__ xb,
    float* __restrict__ as_, float* __restrict__ ad_)
{
    const int t = threadIdx.x;
    const int n = blockIdx.x * 4 + (t >> 6);
    const int lane = t & 63;
    const int f0 = lane * 2;
    float m0 = bnsum[f0] * (1.0f / NN);
    float v0 = bnsum[128 + f0] * (1.0f / NN) - m0 * m0;
    float m1 = bnsum[f0 + 1] * (1.0f / NN);
    float v1 = bnsum[128 + f0 + 1] * (1.0f / NN) - m1 * m1;
    float sc0 = g[f0] * rsqrtf(v0 + BN_EPS);
    float sc1 = g[f0 + 1] * rsqrtf(v1 + BN_EPS);
    float sh0 = beta[f0] - m0 * sc0;
    float sh1 = beta[f0 + 1] - m1 * sc1;

    unsigned pv = ((const unsigned*)y16)[(size_t)n * 64 + lane];
    float2 xv;
    xv.x = bf2f((unsigned short)(pv & 0xFFFFu)) * sc0 + sh0;
    xv.y = bf2f((unsigned short)(pv >> 16)) * sc1 + sh1;
    unsigned pk = (unsigned)f2bf(xv.x) | ((unsigned)f2bf(xv.y) << 16);
    ((unsigned*)xb)[(size_t)n * 64 + lane] = pk;
    if (do_proj) {
        float2 aws = ((const float2*)attW)[lane];
        float2 awd = ((const float2*)(attW + 128))[lane];
        float pas = xv.x * aws.x + xv.y * aws.y;
        float pad = xv.x * awd.x + xv.y * awd.y;
#pragma unroll
        for (int msk = 32; msk >= 1; msk >>= 1) {
            pas += __shfl_xor(pas, msk);
            pad += __shfl_xor(pad, msk);
        }
        if (lane == 0) { as_[n] = pas; ad_[n] = pad; }
    }
}

// ---------------------------------------------------------------------------
// Combined-weight precompute: Wc[l] = Wih[l] @ Wm[l], bmih[l] = Wih[l] @ bm[l]
// ---------------------------------------------------------------------------
__global__ __launch_bounds__(128) void k_wc(
    const float* __restrict__ Wih, const float* __restrict__ Wm,
    const float* __restrict__ bm, float* __restrict__ Wc, float* __restrict__ bmih)
{
    __shared__ float sw[128];
    __shared__ float red[128];
    const int b = blockIdx.x;
    const int l = b / 384, r = b - l * 384;
    const int t = threadIdx.x;
    const float* wihrow = Wih + ((size_t)l * 384 + r) * 128;
    sw[t] = wihrow[t];
    __syncthreads();
    const float* wm = Wm + (size_t)l * 128 * 128;
    float acc = 0.f;
#pragma unroll 8
    for (int k = 0; k < 128; k++) acc += sw[k] * wm[k * 128 + t];
    Wc[((size_t)l * 384 + r) * 128 + t] = acc;
    red[t] = sw[t] * bm[l * 128 + t];
    __syncthreads();
#pragma unroll
    for (int off = 64; off >= 1; off >>= 1) {
        if (t < off) red[t] += red[t + off];
        __syncthreads();
    }
    if (t == 0) bmih[l * 384 + r] = red[0];
}

// ---------------------------------------------------------------------------
// Convert Wc (fp32) and Whh to bf16 in MFMA B-fragment order:
//   layout [gate(3)][tc(8)][kb(4)][quad(4)][n(16)][j(8)] per layer-matrix
// ---------------------------------------------------------------------------
__global__ __launch_bounds__(256) void k_frag(
    const float* __restrict__ Wc, const float* __restrict__ Whh,
    unsigned short* __restrict__ wcb, unsigned short* __restrict__ whhb)
{
    const int b = blockIdx.x;
    const int mat = b / 192;
    const int e = (b - mat * 192) * 256 + threadIdx.x;   // 0..49151
    const int l = mat >> 1, which = mat & 1;
    const float* src = which ? (Whh + (size_t)l * 49152) : (Wc + (size_t)l * 49152);
    unsigned short* dst = which ? (whhb + (size_t)l * 49152) : (wcb + (size_t)l * 49152);
    int j = e & 7, n = (e >> 3) & 15, quad = (e >> 7) & 3;
    int kb = (e >> 9) & 3, tc = (e >> 11) & 7, g = (e >> 14) & 3;
    int row = g * 128 + tc * 16 + n;
    int kk = kb * 32 + quad * 8 + j;
    dst[e] = f2bf(src[row * 128 + kk]);
}

// ---------------------------------------------------------------------------
// CSR build: histogram, 3-kernel device-wide scan, scatter
// ---------------------------------------------------------------------------
__global__ __launch_bounds__(256) void k_count(const int* __restrict__ dst, int* __restrict__ cnt)
{
    int e = blockIdx.x * 256 + threadIdx.x;
    if (e < NE) atomicAdd(&cnt[dst[e]], 1);
}

#define SCAN_B 512
#define SCAN_G 98          // 98*512 = 50176 >= 50000

__global__ __launch_bounds__(SCAN_B) void k_scan1(
    const int* __restrict__ cnt, int* __restrict__ rowptr, int* __restrict__ bsum)
{
    __shared__ int s[SCAN_B];
    const int t = threadIdx.x;
    const int i = blockIdx.x * SCAN_B + t;
    int v = (i < NN) ? cnt[i] : 0;
    s[t] = v;
    __syncthreads();
#pragma unroll
    for (int off = 1; off < SCAN_B; off <<= 1) {
        int u = (t >= off) ? s[t - off] : 0;
        __syncthreads();
        s[t] += u;
        __syncthreads();
    }
    if (i < NN) rowptr[i] = s[t] - v;        // local exclusive
    if (t == SCAN_B - 1) bsum[blockIdx.x] = s[t];
}

__global__ __launch_bounds__(128) void k_scan2(int* __restrict__ bsum, int* __restrict__ rowptr)
{
    __shared__ int s[128];
    const int t = threadIdx.x;
    int v = (t < SCAN_G) ? bsum[t] : 0;
    s[t] = v;
    __syncthreads();
#pragma unroll
    for (int off = 1; off < 128; off <<= 1) {
        int u = (t >= off) ? s[t - off] : 0;
        __syncthreads();
        s[t] += u;
        __syncthreads();
    }
    if (t < SCAN_G) bsum[t] = s[t] - v;      // exclusive offsets
    if (t == 127) rowptr[NN] = s[127];       // grand total (= NE)
}

__global__ __launch_bounds__(SCAN_B) void k_scan3(
    int* __restrict__ rowptr, const int* __restrict__ bsum, int* __restrict__ wptr)
{
    const int i = blockIdx.x * SCAN_B + threadIdx.x;
    if (i < NN) {
        int v = rowptr[i] + bsum[blockIdx.x];
        rowptr[i] = v;
        wptr[i] = v;
    }
}

__global__ __launch_bounds__(256) void k_scatter(
    const int* __restrict__ src, const int* __restrict__ dst,
    int* __restrict__ wptr, int* __restrict__ ssrc)
{
    int e = blockIdx.x * 256 + threadIdx.x;
    if (e < NE) {
        int d = dst[e];
        int pos = atomicAdd(&wptr[d], 1);
        ssrc[pos] = src[e];
    }
}

// ---------------------------------------------------------------------------
// Gather-aggregate, batched + id-PIPELINED. block 256 = 8 nodes x 32 lanes.
// R22 lesson: keep gather in its OWN high-TLP geometry (6250 light blocks);
// fusing it into the GRU's 391 heavy blocks collapsed its latency hiding.
// ---------------------------------------------------------------------------
__global__ __launch_bounds__(256) void k_gather(
    const int* __restrict__ rowptr, const int* __restrict__ ssrc,
    const unsigned short* __restrict__ xb, const float* __restrict__ as_,
    const float* __restrict__ ad_, const float* __restrict__ attb, int l,
    unsigned short* __restrict__ aggxb, float* __restrict__ sumatt)
{
    const int t = threadIdx.x;
    const int n = blockIdx.x * 8 + (t >> 5);
    const int lane = t & 31;
    const int r0 = rowptr[n], r1 = rowptr[n + 1];
    const float adv = ad_[n] + attb[l];
    float4 acc = make_float4(0.f, 0.f, 0.f, 0.f);
    float satt = 0.f;

    int ids[8], ids2[8];
    if (r0 < r1) {
#pragma unroll
        for (int k = 0; k < 8; k++) {
            int idx = r0 + k; if (idx >= r1) idx = r1 - 1;
            ids[k] = ssrc[idx];
        }
    }
    for (int base = r0; base < r1; base += 8) {
        const int nxt = base + 8;
        if (nxt < r1) {
#pragma unroll
            for (int k = 0; k < 8; k++) {
                int idx = nxt + k; if (idx >= r1) idx = r1 - 1;
                ids2[k] = ssrc[idx];
            }
        }
        ushort4 v[8];
        float a[8];
#pragma unroll
        for (int k = 0; k < 8; k++) {
            v[k] = ((const ushort4*)xb)[(size_t)ids[k] * 32 + lane];
            a[k] = as_[ids[k]];
        }
#pragma unroll
        for (int k = 0; k < 8; k++) {
            if (base + k < r1) {
                float att = sigm(a[k] + adv);
                acc.x += bf2f(v[k].x) * att; acc.y += bf2f(v[k].y) * att;
                acc.z += bf2f(v[k].z) * att; acc.w += bf2f(v[k].w) * att;
                satt += att;
            }
        }
#pragma unroll
        for (int k = 0; k < 8; k++) ids[k] = ids2[k];
    }
    ushort4 o;
    o.x = f2bf(acc.x); o.y = f2bf(acc.y); o.z = f2bf(acc.z); o.w = f2bf(acc.w);
    ((ushort4*)aggxb)[(size_t)n * 32 + lane] = o;
    if (lane == 0) sumatt[n] = satt;
}

// ---------------------------------------------------------------------------
// MFMA GRU — R20 geometry (512 thr / 8 waves, 128 nodes/block, grid 391).
// R23: y stored BF16 (halves the pre-BN stream); BN partials from the
// rounded h for self-consistency with what BN applies to.
// R16-R20 established: intra-kernel schedule is NOT the lever (~51 us
// invariant across serial/pipelined/occupancy variants).
// R19: never add node-tiles per wave (VGPR blowup). R22: never fuse gather
// in here (TLP collapse). R11/R13: no occupancy forcing. R8: no col split.
// ---------------------------------------------------------------------------
#define STAGE_W(SRC)                                                          \
    {                                                                         \
        const char* gsrc = (const char*)(SRC) + wave * 4096 + lane * 16;      \
        char* ldst = (char*)wbuf + wave * 4096;                               \
        _Pragma("unroll")                                                     \
        for (int i = 0; i < 4; i++)                                           \
            gl2lds16(gsrc + i * 1024, ldst + i * 1024);                       \
    }

#define MMGL(AF, ACC)                                                         \
    _Pragma("unroll")                                                         \
    for (int tc = 0; tc < 8; tc++) {                                          \
        bhalf8 bfr[4];                                                        \
        _Pragma("unroll")                                                     \
        for (int kb = 0; kb < 4; kb++)                                        \
            bfr[kb] = *(const bhalf8*)&wbuf[((tc * 4 + kb) * 64 + lane) * 8]; \
        _Pragma("unroll")                                                     \
        for (int kb = 0; kb < 4; kb++)                                        \
            ACC[tc] = __builtin_amdgcn_mfma_f32_16x16x32_bf16(AF[kb], bfr[kb], ACC[tc], 0, 0, 0); \
    }

__global__ __launch_bounds__(512) void k_gru(
    const unsigned short* __restrict__ aggxb, const float* __restrict__ sumatt,
    const unsigned short* __restrict__ xb,
    const unsigned short* __restrict__ wcb, const float* __restrict__ bmih,
    const float* __restrict__ bih,
    const unsigned short* __restrict__ whhb, const float* __restrict__ bhh,
    unsigned short* __restrict__ y16, float* __restrict__ bnsum)
{
    __shared__ __align__(16) unsigned short wbuf[16384];   // 32 KB weight stage
    __shared__ float sred[1024], sred2[1024];              // 8 KB BN partials
    const int t = threadIdx.x;
    const int wave = t >> 6, lane = t & 63;
    const int col = lane & 15, quad = (lane >> 4) & 3;
    const int node0 = blockIdx.x * 128;

    STAGE_W(wcb + 0 * 16384);    // issue gate-r Wc stage before A loads

    const int anode = node0 + wave * 16 + col;
    bhalf8 afA[4], afX[4];
#pragma unroll
    for (int kb = 0; kb < 4; kb++) {
        afA[kb] = *(const bhalf8*)&aggxb[(size_t)anode * HID + kb * 32 + quad * 8];
        afX[kb] = *(const bhalf8*)&xb[(size_t)anode * HID + kb * 32 + quad * 8];
    }
    float sa[4];
#pragma unroll
    for (int e = 0; e < 4; e++) sa[e] = sumatt[node0 + wave * 16 + quad * 4 + e];

    floatx4 accR[8], accN[8];

    // ===== gate r: merged accumulator (gi+gh) =====
#pragma unroll
    for (int tc = 0; tc < 8; tc++) {
        int f = 0 * 128 + tc * 16 + col;
        float b0 = bih[f] + bhh[f], bm = bmih[f];
        accR[tc] = (floatx4){b0 + sa[0] * bm, b0 + sa[1] * bm, b0 + sa[2] * bm, b0 + sa[3] * bm};
    }
    __syncthreads();                 // wcb[r] staged (drains vmcnt)
    MMGL(afA, accR);
    __syncthreads();                 // all waves done reading
    STAGE_W(whhb + 0 * 16384);
    __syncthreads();
    MMGL(afX, accR);
    __syncthreads();
    STAGE_W(whhb + 2 * 16384);       // prefetch gate-n Whh; sigm overlaps
#pragma unroll
    for (int tc = 0; tc < 8; tc++)
#pragma unroll
        for (int e = 0; e < 4; e++)
            accR[tc][e] = sigm(accR[tc][e]);          // accR now holds r

    // ===== gate n: acc = afX@Whh + bh; acc = r*acc + bi + sa*bm; acc += afA@Wc =====
#pragma unroll
    for (int tc = 0; tc < 8; tc++) {
        float bh = bhh[2 * 128 + tc * 16 + col];
        accN[tc] = (floatx4){bh, bh, bh, bh};
    }
    __syncthreads();
    MMGL(afX, accN);
    __syncthreads();
    STAGE_W(wcb + 2 * 16384);        // prefetch gate-n Wc; r-merge overlaps
#pragma unroll
    for (int tc = 0; tc < 8; tc++) {
        int f = 2 * 128 + tc * 16 + col;
        float bi = bih[f], bm = bmih[f];
#pragma unroll
        for (int e = 0; e < 4; e++)
            accN[tc][e] = accR[tc][e] * accN[tc][e] + bi + sa[e] * bm;
    }
    __syncthreads();
    MMGL(afA, accN);
    __syncthreads();
    STAGE_W(wcb + 1 * 16384);        // prefetch gate-z Wc; tanh overlaps
#pragma unroll
    for (int tc = 0; tc < 8; tc++)
#pragma unroll
        for (int e = 0; e < 4; e++)
            accN[tc][e] = tanh_f(accN[tc][e]);        // accN now holds n

    // ===== gate z: merged accumulator (reuse accR) =====
#pragma unroll
    for (int tc = 0; tc < 8; tc++) {
        int f = 1 * 128 + tc * 16 + col;
        float b0 = bih[f] + bhh[f], bm = bmih[f];
        accR[tc] = (floatx4){b0 + sa[0] * bm, b0 + sa[1] * bm, b0 + sa[2] * bm, b0 + sa[3] * bm};
    }
    __syncthreads();
    MMGL(afA, accR);
    __syncthreads();
    STAGE_W(whhb + 1 * 16384);
    __syncthreads();
    MMGL(afX, accR);

    // ===== h = (1-z)*n + z*x; bf16 y stores; BN partials from rounded h =====
    float ps[8], ps2[8];
#pragma unroll
    for (int tc = 0; tc < 8; tc++) {
        ps[tc] = 0.f; ps2[tc] = 0.f;
#pragma unroll
        for (int e = 0; e < 4; e++) {
            float z = sigm(accR[tc][e]);
            int nd = node0 + wave * 16 + quad * 4 + e;
            float xv = bf2f(xb[(size_t)nd * HID + tc * 16 + col]);
            float h = (1.0f - z) * accN[tc][e] + z * xv;
            if (nd < NN) {
                unsigned short hb = f2bf(h);
                float hr = bf2f(hb);
                y16[(size_t)nd * HID + tc * 16 + col] = hb;
                ps[tc] += hr; ps2[tc] += hr * hr;
            }
        }
    }
#pragma unroll
    for (int tc = 0; tc < 8; tc++) {
        ps[tc]  += __shfl_xor(ps[tc], 16);  ps2[tc] += __shfl_xor(ps2[tc], 16);
        ps[tc]  += __shfl_xor(ps[tc], 32);  ps2[tc] += __shfl_xor(ps2[tc], 32);
    }
    if (quad == 0) {
#pragma unroll
        for (int tc = 0; tc < 8; tc++) {
            sred[wave * 128 + tc * 16 + col]  = ps[tc];
            sred2[wave * 128 + tc * 16 + col] = ps2[tc];
        }
    }
    __syncthreads();
    if (t < 128) {
        float s = 0.f, s2 = 0.f;
#pragma unroll
        for (int w = 0; w < 8; w++) { s += sred[w * 128 + t]; s2 += sred2[w * 128 + t]; }
        unsafeAtomicAdd(&bnsum[t], s);
        unsafeAtomicAdd(&bnsum[128 + t], s2);
    }
}

// ---------------------------------------------------------------------------
// Segmented sum-pool over bf16 xb (batch_idx is SORTED)
// ---------------------------------------------------------------------------
__global__ __launch_bounds__(256) void k_pool(
    const unsigned short* __restrict__ xb, const int* __restrict__ batch,
    float* __restrict__ gr)
{
    __shared__ int sb[256];
    const int t = threadIdx.x;
    const int nb = blockIdx.x * 256;
    int ld = nb + t; if (ld >= NN) ld = NN - 1;
    sb[t] = batch[ld];
    __syncthreads();
    const int s = t >> 7, f = t & 127;
    float acc = 0.f; int cur = -1;
    for (int i = s; i < 256; i += 2) {
        int n = nb + i;
        if (n >= NN) break;
        int g = sb[i];
        if (g != cur) {
            if (cur >= 0) unsafeAtomicAdd(&gr[(size_t)cur * HID + f], acc);
            acc = 0.f; cur = g;
        }
        acc += bf2f(xb[(size_t)n * HID + f]);
    }
    if (cur >= 0) unsafeAtomicAdd(&gr[(size_t)cur * HID + f], acc);
}

// ---------------------------------------------------------------------------
// Readout: out[g] = relu(gr[g] @ W1^T + b1) @ W2^T + b2   (128 blocks x 64)
// ---------------------------------------------------------------------------
__global__ __launch_bounds__(64) void k_readout(
    const float* __restrict__ gr, const float* __restrict__ W1,
    const float* __restrict__ b1, const float* __restrict__ W2,
    const float* __restrict__ b2, float* __restrict__ out)
{
    const int g = blockIdx.x, j = threadIdx.x;
    float acc = b1[j];
    const float4* grow = (const float4*)&gr[g * HID];
    const float4* wrow = (const float4*)&W1[j * HID];
#pragma unroll
    for (int k4 = 0; k4 < 32; k4++) {
        float4 a = grow[k4], w = wrow[k4];
        acc += a.x * w.x + a.y * w.y + a.z * w.z + a.w * w.w;
    }
    float h = fmaxf(acc, 0.0f) * W2[j];
#pragma unroll
    for (int msk = 32; msk >= 1; msk >>= 1) h += __shfl_xor(h, msk);
    if (j == 0) out[g] = h + b2[0];
}

// ---------------------------------------------------------------------------
extern "C" void kernel_launch(void* const* d_in, const int* in_sizes, int n_in,
                              void* d_out, int out_size, void* d_ws, size_t ws_size,
                              hipStream_t stream)
{
    const float* nf    = (const float*)d_in[0];
    const int*   ei    = (const int*)d_in[1];
    const int*   batch = (const int*)d_in[2];
    const float* embW  = (const float*)d_in[3];
    const float* embb  = (const float*)d_in[4];
    const float* embg  = (const float*)d_in[5];
    const float* embbe = (const float*)d_in[6];
    const float* msgW  = (const float*)d_in[7];
    const float* msgb  = (const float*)d_in[8];
    const float* attW  = (const float*)d_in[9];
    const float* attb  = (const float*)d_in[10];
    const float* Wih   = (const float*)d_in[11];
    const float* bih   = (const float*)d_in[12];
    const float* Whh   = (const float*)d_in[13];
    const float* bhh   = (const float*)d_in[14];
    const float* bng   = (const float*)d_in[15];
    const float* bnb   = (const float*)d_in[16];
    const float* roW1  = (const float*)d_in[17];
    const float* rob1  = (const float*)d_in[18];
    const float* roW2  = (const float*)d_in[19];
    const float* rob2  = (const float*)d_in[20];
    const int* src = ei;
    const int* dst = ei + NE;
    float* out = (float*)d_out;

    // ---- workspace layout (all sections 16B-multiple) ----
    char* base = (char*)d_ws;
    const size_t NHP = (size_t)NNP * HID;    // padded rows
    float* bnsum = (float*)base;             // 5 slots x 256 floats (10240 B reserved)
    unsigned short* y16   = (unsigned short*)(base + 10240); // bf16 pre-BN state
    unsigned short* xb    = y16 + NHP;                       // bf16 node state
    unsigned short* aggxb = xb + NHP;                        // bf16 gather output
    float* as_   = (float*)(aggxb + NHP);
    float* ad_   = as_ + NN;
    float* sumatt= ad_ + NN;                 // NNP floats (padded reads in k_gru)
    float* gr    = sumatt + NNP;             // 128*128
    float* Wc    = gr + NGRAPHS * HID;       // 4*384*128 fp32
    float* bmih  = Wc + 4 * 384 * 128;       // 4*384
    int* rowptr  = (int*)(bmih + 4 * 384);   // NN+4 (padded for alignment)
    int* wptr    = rowptr + NN + 4;          // NN
    int* cnt     = wptr + NN;                // NN
    int* bsum    = cnt + NN;                 // 128 (scan block totals)
    int* ssrc    = bsum + 128;               // NE
    unsigned short* wcb  = (unsigned short*)(ssrc + NE); // 4*49152 bf16 frags
    unsigned short* whhb = wcb + 4 * 49152;              // 4*49152 bf16 frags
    unsigned short* nfb  = whhb + 4 * 49152;             // NNP*96 bf16 padded nf
    unsigned short* web  = nfb + (size_t)NNP * 96;       // 12288 emb B-frags

    // ---- once-per-call precompute: weights (+bf16 frags), nf cast, CSR ----
    k_wc<<<4 * 384, 128, 0, stream>>>(Wih, msgW, msgb, Wc, bmih);
    k_frag<<<8 * 192, 256, 0, stream>>>(Wc, Whh, wcb, whhb);
    k_nfb<<<(NN * 24 + 255) / 256, 256, 0, stream>>>(nf, nfb);
    k_wfrag_emb<<<48, 256, 0, stream>>>(embW, web);
    hipMemsetAsync(cnt, 0, NN * sizeof(int), stream);
    hipMemsetAsync(bnsum, 0, 5 * 256 * sizeof(float), stream);
    k_count<<<(NE + 255) / 256, 256, 0, stream>>>(dst, cnt);
    k_scan1<<<SCAN_G, SCAN_B, 0, stream>>>(cnt, rowptr, bsum);
    k_scan2<<<1, 128, 0, stream>>>(bsum, rowptr);
    k_scan3<<<SCAN_G, SCAN_B, 0, stream>>>(rowptr, bsum, wptr);
    k_scatter<<<(NE + 255) / 256, 256, 0, stream>>>(src, dst, wptr, ssrc);

    // ---- MFMA embedding (BN sums -> slot 0) + fused BN/att-proj ----
    k_embed_m<<<NB128, 512, 0, stream>>>(nfb, web, embb, y16, bnsum);
    k_bnx<<<NN / 4, 256, 0, stream>>>(y16, bnsum, embg, embbe, attW, 1, xb, as_, ad_);

    for (int l = 0; l < NLAYERS; l++) {
        k_gather<<<NN / 8, 256, 0, stream>>>(rowptr, ssrc, xb, as_, ad_, attb, l, aggxb, sumatt);
        k_gru<<<NB128, 512, 0, stream>>>(
            aggxb, sumatt, xb,
            wcb + (size_t)l * 49152, bmih + (size_t)l * 384, bih + (size_t)l * 384,
            whhb + (size_t)l * 49152, bhh + (size_t)l * 384, y16, bnsum + (l + 1) * 256);
        const int do_proj = (l + 1 < NLAYERS) ? 1 : 0;
        const float* attW_next = attW + (size_t)((l + 1 < NLAYERS) ? l + 1 : l) * 256;
        k_bnx<<<NN / 4, 256, 0, stream>>>(y16, bnsum + (l + 1) * 256,
                                          bng + (size_t)l * HID, bnb + (size_t)l * HID,
                                          attW_next, do_proj, xb, as_, ad_);
    }

    hipMemsetAsync(gr, 0, NGRAPHS * HID * sizeof(float), stream);
    k_pool<<<(NN + 255) / 256, 256, 0, stream>>>(xb, batch, gr);
    k_readout<<<NGRAPHS, 64, 0, stream>>>(gr, roW1, rob1, roW2, rob2, out);
}